// Round 7
// baseline (140.305 us; speedup 1.0000x reference)
//
#include <hip/hip_runtime.h>

typedef unsigned int u32;
typedef unsigned short u16;
typedef __attribute__((ext_vector_type(8))) __bf16 bf16x8;
typedef __attribute__((ext_vector_type(4))) float f32x4;

#define B_SZ 2048
#define IN_SZ 1024
#define K_SZ 128
#define E_SZ 64
#define TWOE 128
#define BK 32
static const size_t OUT_EMB = (size_t)B_SZ * K_SZ * E_SZ;  // 16,777,216

__device__ __forceinline__ u16 f2bf(float f) {
    u32 u = __builtin_bit_cast(u32, f);
    u32 r = u + 0x7fffu + ((u >> 16) & 1u);
    return (u16)(r >> 16);
}

__device__ __forceinline__ void async16(const void* g, void* l) {
    __builtin_amdgcn_global_load_lds((const __attribute__((address_space(1))) u32*)g,
                                     (__attribute__((address_space(3))) u32*)l, 16, 0, 0);
}

// ---------------- conversion kernels ----------------
__global__ void __launch_bounds__(256) cvt_x(const float* __restrict__ in, u16* __restrict__ outp, int n4) {
    int i = blockIdx.x * blockDim.x + threadIdx.x;
    if (i < n4) {
        float4 v = ((const float4*)in)[i];
        u32 lo = (u32)f2bf(v.x) | ((u32)f2bf(v.y) << 16);
        u32 hi = (u32)f2bf(v.z) | ((u32)f2bf(v.w) << 16);
        ((uint2*)outp)[i] = make_uint2(lo, hi);
    }
}

// W[k][i][o] f32 -> Wt[k][o][i] bf16.  grid (16 i-blocks, 128 k), 256 thr
__global__ void __launch_bounds__(256) cvt_w(const float* __restrict__ W, u16* __restrict__ wt) {
    __shared__ u16 tr[128][72];
    const int k = blockIdx.y, i0 = blockIdx.x * 64;
    const float* src = W + (size_t)k * IN_SZ * TWOE + (size_t)i0 * TWOE;
#pragma unroll
    for (int r = 0; r < 8; ++r) {
        int idx = r * 256 + threadIdx.x;
        int i = idx >> 5;
        int o = (idx & 31) * 4;
        float4 v = ((const float4*)src)[idx];
        tr[o + 0][i] = f2bf(v.x);
        tr[o + 1][i] = f2bf(v.y);
        tr[o + 2][i] = f2bf(v.z);
        tr[o + 3][i] = f2bf(v.w);
    }
    __syncthreads();
    const int o = threadIdx.x >> 1, h = threadIdx.x & 1;
    u16* dst = wt + ((size_t)(k * TWOE + o) * IN_SZ) + i0 + h * 32;
#pragma unroll
    for (int s = 0; s < 4; ++s) {
        uint4 v = *(const uint4*)&tr[o][h * 32 + s * 8];
        ((uint4*)dst)[s] = v;
    }
}

// pw[k][b] -> out_pred[b][k] transpose, 16 blocks x 256 thr
__global__ void __launch_bounds__(256) cvt_pred(const float* __restrict__ pw, float* __restrict__ out) {
    __shared__ float t[128][132];
    const int b0 = blockIdx.x * 128;
    const int tid = threadIdx.x;
#pragma unroll
    for (int i = 0; i < 16; ++i) {
        int idx = i * 256 + tid;
        int kk = idx >> 5, c4 = (idx & 31) * 4;
        float4 v = *(const float4*)(pw + (size_t)kk * B_SZ + b0 + c4);
        t[kk][c4 + 0] = v.x; t[kk][c4 + 1] = v.y; t[kk][c4 + 2] = v.z; t[kk][c4 + 3] = v.w;
    }
    __syncthreads();
#pragma unroll
    for (int i = 0; i < 16; ++i) {
        int idx = i * 256 + tid;
        int bl = idx >> 5, k4 = (idx & 31) * 4;
        float4 v = make_float4(t[k4 + 0][bl], t[k4 + 1][bl], t[k4 + 2][bl], t[k4 + 3][bl]);
        *(float4*)(out + OUT_EMB + (size_t)(b0 + bl) * K_SZ + k4) = v;
    }
}

// ---------------- fused GEMM + epilogue ----------------
// BM=256, BN=128(=TWOE), BK=32. 256 threads = 4 waves (2M x 2N), per-wave 128x64.
// A: 3-buffer LDS ring (48 KB). B: direct global->VGPR from L2, REGISTER
// DOUBLE-BUFFERED one iteration ahead (R6's same-iter load exposed ~900 cyc
// of L2 latency per step). Counted vmcnt(8) keeps B(t+1)+A(t+2) in flight.
// grid: 1024 blocks (8 brow x 128 k), XCD-chunked: each XCD owns 16 consecutive k.
__global__ void __launch_bounds__(256, 2) fused_main(
    const u16* __restrict__ xb,   // [B][IN] bf16
    const u16* __restrict__ wt,   // [K][2E][IN] bf16
    const float* __restrict__ bias, const float* __restrict__ wpv,
    const float* __restrict__ bpp, float* __restrict__ out,
    float* __restrict__ pw) {
    __shared__ union {
        u16 stage[3][8192];   // per buf: A[256][32] bf16, 16 KB
        struct { float pl[256][2]; float ex[128][65]; } epi;
    } sm;

    const int tid = threadIdx.x;
    const int l = tid & 63, w = tid >> 6;   // lane, wave 0..3
    const int wm = w >> 1, wn = w & 1;      // 2M x 2N
    const int hi = l >> 4, lo16 = l & 15;
    const int q = l >> 2, sl = l & 3;       // staging: row-in-16, 16B slot

    // XCD-aware (k,brow) mapping: each XCD owns 16 consecutive k;
    // 8 consecutive blocks share k (brow varies) -> Wt k-slice stays L2-hot.
    const int id = blockIdx.x;
    const int xcd = id & 7, j2 = id >> 3;   // j2: 0..127
    const int k = (xcd << 4) | (j2 >> 3);
    const int brow = (j2 & 7) << 8;         // *256

    // A staging: LDS dest linear; SOURCE k-slot pre-swizzled (involution slot^((row>>1)&3))
    const u16* abase = xb + (size_t)(brow + w * 16 + q) * IN_SZ + (sl ^ ((q >> 1) & 3)) * 8;

    // A ds_read fragment offsets (bytes), same involution on the read side
    const int xsl = (hi ^ ((lo16 >> 1) & 3)) << 4;
    const int aoff = (wm * 128 + lo16) * 64 + xsl;         // + m*1024

    // B fragment global base: row o = wn*64 + n*16 + lo16, k-elems hi*8..hi*8+7
    const u16* bprow = wt + ((size_t)k * TWOE + wn * 64 + lo16) * IN_SZ + hi * 8;

    f32x4 acc[8][4] = {};
    bf16x8 bfr[2][4];   // register double-buffer for B (statically indexed)

    auto STAGE = [&](int bi, int tt) {
        const int koff = tt * BK;
        u16* sbuf = &sm.stage[bi][0];
#pragma unroll
        for (int i = 0; i < 4; ++i)   // A rows i*64 + w*16 + q
            async16(abase + (size_t)i * 64 * IN_SZ + koff, sbuf + i * 2048 + w * 512);
    };

    // hoist epilogue params (overlaps with K-loop)
    const float bp_val = *bpp;
    float bvals[4], wvals[4];
#pragma unroll
    for (int n = 0; n < 4; ++n) {
        const int o = wn * 64 + n * 16 + lo16;
        bvals[n] = bias[k * TWOE + o];
        wvals[n] = wpv[o];
    }

    // prologue: A(0),A(1) DMA; B(0) into bfr[0]
    STAGE(0, 0);
    STAGE(1, 1);
#pragma unroll
    for (int n = 0; n < 4; ++n)
        bfr[0][n] = *(const bf16x8*)(bprow + (size_t)n * 16 * IN_SZ);
    // A(0) retired when <=8 outstanding (A(1)x4 + B(0)x4 may remain)
    asm volatile("s_waitcnt vmcnt(8)" ::: "memory");
    __builtin_amdgcn_s_barrier();

// one K-step: prefetch B(T+1) into bfr[NXT], stage A(T+2), compute with bfr[CUR]
#define STEP(T, CUR, NXT, PF, ST, VMW)                                          \
    {                                                                           \
        if (PF) {                                                               \
            _Pragma("unroll")                                                   \
            for (int n = 0; n < 4; ++n)                                         \
                bfr[NXT][n] = *(const bf16x8*)(bprow + (size_t)n * 16 * IN_SZ + ((T) + 1) * 32); \
        }                                                                       \
        if (ST) STAGE(((T) + 2) % 3, (T) + 2);                                  \
        const char* base_ = (const char*)&sm.stage[(T) % 3][0];                 \
        bf16x8 af[8];                                                           \
        _Pragma("unroll")                                                       \
        for (int m = 0; m < 8; ++m)                                             \
            af[m] = *(const bf16x8*)(base_ + aoff + m * 1024);                  \
        __builtin_amdgcn_s_setprio(1);                                          \
        _Pragma("unroll")                                                       \
        for (int m = 0; m < 8; ++m)                                             \
            _Pragma("unroll")                                                   \
            for (int n = 0; n < 4; ++n)                                         \
                acc[m][n] = __builtin_amdgcn_mfma_f32_16x16x32_bf16(af[m], bfr[CUR][n], acc[m][n], 0, 0, 0); \
        __builtin_amdgcn_s_setprio(0);                                          \
        asm volatile("s_waitcnt " VMW " lgkmcnt(0)" ::: "memory");              \
        __builtin_amdgcn_s_barrier();                                           \
    }

#pragma unroll 1
    for (int t = 0; t < 30; t += 2) {
        STEP(t, 0, 1, true, true, "vmcnt(8)");
        STEP(t + 1, 1, 0, true, (t + 1) < 30, "vmcnt(8)");
    }
    STEP(30, 0, 1, true, false, "vmcnt(4)");    // loads B(31) only
    STEP(31, 1, 0, false, false, "vmcnt(0)");   // drain
#undef STEP

    // ---- epilogue ----
    float p[8][4];   // dot partial -> c_pred
#pragma unroll
    for (int m = 0; m < 8; ++m)
#pragma unroll
        for (int j = 0; j < 4; ++j) {
            float s = 0.f;
#pragma unroll
            for (int n = 0; n < 4; ++n) {
                float v = acc[m][n][j] + bvals[n];
                v = v > 0.f ? v : 0.01f * v;
                acc[m][n][j] = v;           // ctx stored back into acc
                s += v * wvals[n];
            }
            s += __shfl_xor(s, 1);
            s += __shfl_xor(s, 2);
            s += __shfl_xor(s, 4);
            s += __shfl_xor(s, 8);
            p[m][j] = s;
        }
    if (lo16 == 0) {
#pragma unroll
        for (int m = 0; m < 8; ++m)
#pragma unroll
            for (int j = 0; j < 4; ++j)
                sm.epi.pl[wm * 128 + m * 16 + hi * 4 + j][wn] = p[m][j];
    }
    __builtin_amdgcn_s_barrier();
#pragma unroll
    for (int m = 0; m < 8; ++m)
#pragma unroll
        for (int j = 0; j < 4; ++j) {
            const int rg = wm * 128 + m * 16 + hi * 4 + j;
            const float z = sm.epi.pl[rg][0] + sm.epi.pl[rg][1] + bp_val;
            p[m][j] = 1.f / (1.f + __expf(-z));
        }
    if (wn == 0 && lo16 == 0) {
        if (pw) {
#pragma unroll
            for (int m = 0; m < 8; ++m) {
                float4 v = make_float4(p[m][0], p[m][1], p[m][2], p[m][3]);
                *(float4*)(pw + (size_t)k * B_SZ + brow + wm * 128 + m * 16 + hi * 4) = v;
            }
        } else {
#pragma unroll
            for (int m = 0; m < 8; ++m)
#pragma unroll
                for (int j = 0; j < 4; ++j) {
                    const int b = brow + wm * 128 + m * 16 + hi * 4 + j;
                    out[OUT_EMB + (size_t)b * K_SZ + k] = p[m][j];
                }
        }
    }
    // c_emb in two 64-row halves per wave (ex fits 128x65 f32 inside 48 KB union)
#pragma unroll
    for (int h = 0; h < 2; ++h) {
        if (wn == 1) {
#pragma unroll
            for (int mm = 0; mm < 4; ++mm) {
                const int m = h * 4 + mm;
#pragma unroll
                for (int n = 0; n < 4; ++n)
#pragma unroll
                    for (int j = 0; j < 4; ++j)
                        sm.epi.ex[wm * 64 + mm * 16 + hi * 4 + j][n * 16 + lo16] =
                            (1.f - p[m][j]) * acc[m][n][j];
            }
        }
        __builtin_amdgcn_s_barrier();
        if (wn == 0) {
#pragma unroll
            for (int mm = 0; mm < 4; ++mm) {
                const int m = h * 4 + mm;
#pragma unroll
                for (int n = 0; n < 4; ++n)
#pragma unroll
                    for (int j = 0; j < 4; ++j) {
                        const int rl = wm * 64 + mm * 16 + hi * 4 + j;
                        const int b = brow + wm * 128 + m * 16 + hi * 4 + j;
                        const int e = n * 16 + lo16;
                        out[((size_t)b * K_SZ + k) * E_SZ + e] =
                            p[m][j] * acc[m][n][j] + sm.epi.ex[rl][e];
                    }
            }
        }
        __builtin_amdgcn_s_barrier();
    }
}

// ---------------- no-ws fallback (correctness insurance) ----------------
__global__ void __launch_bounds__(128) fallback_kernel(
    const float* __restrict__ x, const float* __restrict__ W,
    const float* __restrict__ bias, const float* __restrict__ wpv,
    const float* __restrict__ bpp, float* __restrict__ out) {
    const int k = blockIdx.y;
    const int b0 = blockIdx.x * 8;
    const int o = threadIdx.x;
    __shared__ float xs[8][1024];
    __shared__ float red[2];
    __shared__ float exch[64];
    for (int idx = threadIdx.x; idx < 8 * 1024; idx += 128)
        xs[idx >> 10][idx & 1023] = x[(size_t)(b0 + (idx >> 10)) * IN_SZ + (idx & 1023)];
    __syncthreads();
    float a[8] = {};
    for (int i = 0; i < 1024; ++i) {
        float wv = W[((size_t)k * IN_SZ + i) * TWOE + o];
#pragma unroll
        for (int bb = 0; bb < 8; ++bb) a[bb] += xs[bb][i] * wv;
    }
    const float bo = bias[k * TWOE + o], wo = wpv[o], bpv = *bpp;
    for (int bb = 0; bb < 8; ++bb) {
        float c = a[bb] + bo;
        c = c > 0.f ? c : 0.01f * c;
        float s = c * wo;
        for (int off = 1; off < 64; off <<= 1) s += __shfl_xor(s, off);
        if ((threadIdx.x & 63) == 0) red[threadIdx.x >> 6] = s;
        __syncthreads();
        float p = 1.f / (1.f + expf(-(red[0] + red[1] + bpv)));
        if (o >= 64) exch[o - 64] = (1.f - p) * c;
        __syncthreads();
        if (o < 64) out[((size_t)(b0 + bb) * K_SZ + k) * E_SZ + o] = p * c + exch[o];
        if (o == 0) out[OUT_EMB + (size_t)(b0 + bb) * K_SZ + k] = p;
        __syncthreads();
    }
}

extern "C" void kernel_launch(void* const* d_in, const int* in_sizes, int n_in,
                              void* d_out, int out_size, void* d_ws, size_t ws_size,
                              hipStream_t stream) {
    const float* x = (const float*)d_in[0];
    const float* W = (const float*)d_in[1];
    const float* bias = (const float*)d_in[2];
    const float* wp = (const float*)d_in[3];
    const float* bp = (const float*)d_in[4];
    float* out = (float*)d_out;

    const size_t X_ELEMS = (size_t)B_SZ * IN_SZ;
    const size_t WT_ELEMS = (size_t)K_SZ * TWOE * IN_SZ;
    const size_t PW_ELEMS = (size_t)K_SZ * B_SZ;
    const size_t NEED_BASE = (X_ELEMS + WT_ELEMS) * sizeof(u16);
    const size_t NEED_FULL = NEED_BASE + PW_ELEMS * sizeof(float);

    if (ws_size >= NEED_BASE) {
        u16* xb = (u16*)d_ws;
        u16* wt = xb + X_ELEMS;
        float* pw = (ws_size >= NEED_FULL) ? (float*)(wt + WT_ELEMS) : nullptr;
        int n4 = (int)(X_ELEMS / 4);
        cvt_x<<<dim3((n4 + 255) / 256), 256, 0, stream>>>(x, xb, n4);
        cvt_w<<<dim3(16, 128), 256, 0, stream>>>(W, wt);
        fused_main<<<dim3(1024), 256, 0, stream>>>(xb, wt, bias, wp, bp, out, pw);
        if (pw) cvt_pred<<<dim3(16), 256, 0, stream>>>(pw, out);
    } else {
        fallback_kernel<<<dim3(B_SZ / 8, K_SZ), 128, 0, stream>>>(x, W, bias, wp, bp, out);
    }
}

// Round 8
// 127.057 us; speedup vs baseline: 1.1043x; 1.1043x over previous
//
#include <hip/hip_runtime.h>

typedef unsigned int u32;
typedef unsigned short u16;
typedef __attribute__((ext_vector_type(8))) __bf16 bf16x8;
typedef __attribute__((ext_vector_type(4))) float f32x4;

#define B_SZ 2048
#define IN_SZ 1024
#define K_SZ 128
#define E_SZ 64
#define TWOE 128
#define BK 32
static const size_t OUT_EMB = (size_t)B_SZ * K_SZ * E_SZ;  // 16,777,216

__device__ __forceinline__ u16 f2bf(float f) {
    u32 u = __builtin_bit_cast(u32, f);
    u32 r = u + 0x7fffu + ((u >> 16) & 1u);
    return (u16)(r >> 16);
}

__device__ __forceinline__ void async16(const void* g, void* l) {
    __builtin_amdgcn_global_load_lds((const __attribute__((address_space(1))) u32*)g,
                                     (__attribute__((address_space(3))) u32*)l, 16, 0, 0);
}

// ---------------- conversion kernels ----------------
__global__ void __launch_bounds__(256) cvt_x(const float* __restrict__ in, u16* __restrict__ outp, int n4) {
    int i = blockIdx.x * blockDim.x + threadIdx.x;
    if (i < n4) {
        float4 v = ((const float4*)in)[i];
        u32 lo = (u32)f2bf(v.x) | ((u32)f2bf(v.y) << 16);
        u32 hi = (u32)f2bf(v.z) | ((u32)f2bf(v.w) << 16);
        ((uint2*)outp)[i] = make_uint2(lo, hi);
    }
}

// W[k][i][o] f32 -> Wt[k][o][i] bf16.  grid (16 i-blocks, 128 k), 256 thr
__global__ void __launch_bounds__(256) cvt_w(const float* __restrict__ W, u16* __restrict__ wt) {
    __shared__ u16 tr[128][72];
    const int k = blockIdx.y, i0 = blockIdx.x * 64;
    const float* src = W + (size_t)k * IN_SZ * TWOE + (size_t)i0 * TWOE;
#pragma unroll
    for (int r = 0; r < 8; ++r) {
        int idx = r * 256 + threadIdx.x;
        int i = idx >> 5;
        int o = (idx & 31) * 4;
        float4 v = ((const float4*)src)[idx];
        tr[o + 0][i] = f2bf(v.x);
        tr[o + 1][i] = f2bf(v.y);
        tr[o + 2][i] = f2bf(v.z);
        tr[o + 3][i] = f2bf(v.w);
    }
    __syncthreads();
    const int o = threadIdx.x >> 1, h = threadIdx.x & 1;
    u16* dst = wt + ((size_t)(k * TWOE + o) * IN_SZ) + i0 + h * 32;
#pragma unroll
    for (int s = 0; s < 4; ++s) {
        uint4 v = *(const uint4*)&tr[o][h * 32 + s * 8];
        ((uint4*)dst)[s] = v;
    }
}

// pw[k][b] -> out_pred[b][k] transpose, 16 blocks x 256 thr
__global__ void __launch_bounds__(256) cvt_pred(const float* __restrict__ pw, float* __restrict__ out) {
    __shared__ float t[128][132];
    const int b0 = blockIdx.x * 128;
    const int tid = threadIdx.x;
#pragma unroll
    for (int i = 0; i < 16; ++i) {
        int idx = i * 256 + tid;
        int kk = idx >> 5, c4 = (idx & 31) * 4;
        float4 v = *(const float4*)(pw + (size_t)kk * B_SZ + b0 + c4);
        t[kk][c4 + 0] = v.x; t[kk][c4 + 1] = v.y; t[kk][c4 + 2] = v.z; t[kk][c4 + 3] = v.w;
    }
    __syncthreads();
#pragma unroll
    for (int i = 0; i < 16; ++i) {
        int idx = i * 256 + tid;
        int bl = idx >> 5, k4 = (idx & 31) * 4;
        float4 v = make_float4(t[k4 + 0][bl], t[k4 + 1][bl], t[k4 + 2][bl], t[k4 + 3][bl]);
        *(float4*)(out + OUT_EMB + (size_t)(b0 + bl) * K_SZ + k4) = v;
    }
}

// ---------------- fused GEMM + epilogue ----------------
// BM=128, BN=128(=TWOE), BK=32. 256 threads = 4 waves (2M x 2N), per-wave 64x64
// (acc[4][4] = 64 AGPR). A+B both via global_load_lds into a 3-buffer ring of
// 16 KB bufs (48 KB total -> 3 blocks/CU = 12 waves/CU; R4's 72 KB allowed only 2).
// Counted vmcnt(4): tile t+2's 4 DMAs stay in flight across the barrier.
// grid: 2048 blocks (16 brow x 128 k), XCD-chunked: each XCD owns 16 consecutive k.
__global__ void __launch_bounds__(256, 3) fused_main(
    const u16* __restrict__ xb,   // [B][IN] bf16
    const u16* __restrict__ wt,   // [K][2E][IN] bf16
    const float* __restrict__ bias, const float* __restrict__ wpv,
    const float* __restrict__ bpp, float* __restrict__ out,
    float* __restrict__ pw) {
    __shared__ union {
        u16 stage[3][8192];   // per buf: A[128][32] @ u16 0, B[128][32] @ u16 4096
        struct { float pl[128][2]; float ex[128][65]; } epi;
    } sm;

    const int tid = threadIdx.x;
    const int l = tid & 63, w = tid >> 6;   // lane, wave 0..3
    const int wm = w >> 1, wn = w & 1;      // 2M x 2N
    const int hi = l >> 4, lo16 = l & 15;
    const int q = l >> 2, sl = l & 3;       // staging: row-in-16, 16B slot

    // XCD-aware (k,brow) mapping: each XCD owns 16 consecutive k;
    // 16 consecutive blocks share k (brow varies) -> Wt k-slice stays L2-hot.
    const int id = blockIdx.x;
    const int xcd = id & 7, j2 = id >> 3;   // j2: 0..255
    const int k = (xcd << 4) | (j2 >> 4);
    const int brow = (j2 & 15) << 7;        // *128

    // staging: LDS dest linear; SOURCE k-slot pre-swizzled (involution slot^((row>>1)&3))
    const u16* abase = xb + (size_t)(brow + w * 16 + q) * IN_SZ + (sl ^ ((q >> 1) & 3)) * 8;
    const u16* bbase = wt + ((size_t)k * TWOE + w * 16 + q) * IN_SZ + (sl ^ ((q >> 1) & 3)) * 8;

    // ds_read fragment offsets (bytes), same involution on the read side
    const int xsl = (hi ^ ((lo16 >> 1) & 3)) << 4;
    const int aoff = (wm * 64 + lo16) * 64 + xsl;          // + m*1024
    const int boff = 8192 + (wn * 64 + lo16) * 64 + xsl;   // + n*1024

    f32x4 acc[4][4] = {};

    auto STAGE = [&](int bi, int tt) {
        const int koff = tt * BK;
        u16* sbuf = &sm.stage[bi][0];
#pragma unroll
        for (int i = 0; i < 2; ++i)    // A rows i*64 + w*16 + q
            async16(abase + (size_t)i * 64 * IN_SZ + koff, sbuf + i * 2048 + w * 512);
#pragma unroll
        for (int jj = 0; jj < 2; ++jj) // B rows jj*64 + w*16 + q
            async16(bbase + (size_t)jj * 64 * IN_SZ + koff, sbuf + 4096 + jj * 2048 + w * 512);
    };

    // hoist epilogue params (overlaps with K-loop)
    const float bp_val = *bpp;
    float bvals[4], wvals[4];
#pragma unroll
    for (int n = 0; n < 4; ++n) {
        const int o = wn * 64 + n * 16 + lo16;
        bvals[n] = bias[k * TWOE + o];
        wvals[n] = wpv[o];
    }

    STAGE(0, 0);
    STAGE(1, 1);
    asm volatile("s_waitcnt vmcnt(4)" ::: "memory");
    __builtin_amdgcn_s_barrier();

    for (int t = 0; t < 32; ++t) {
        const int b0 = t % 3;
        if (t < 30) STAGE((b0 + 2) % 3, t + 2);   // tile t+2 into ring slot
        const char* base = (const char*)&sm.stage[b0][0];
        bf16x8 af[4], bfr[4];
#pragma unroll
        for (int m = 0; m < 4; ++m)
            af[m] = *(const bf16x8*)(base + aoff + m * 1024);
#pragma unroll
        for (int n = 0; n < 4; ++n)
            bfr[n] = *(const bf16x8*)(base + boff + n * 1024);
        __builtin_amdgcn_s_setprio(1);
#pragma unroll
        for (int m = 0; m < 4; ++m)
#pragma unroll
            for (int n = 0; n < 4; ++n)
                acc[m][n] = __builtin_amdgcn_mfma_f32_16x16x32_bf16(af[m], bfr[n], acc[m][n], 0, 0, 0);
        __builtin_amdgcn_s_setprio(0);
        // t+1's 4 DMAs (issued at t-1, older) must retire; t+2's 4 stay in flight (T4)
        if (t < 30) asm volatile("s_waitcnt vmcnt(4) lgkmcnt(0)" ::: "memory");
        else        asm volatile("s_waitcnt vmcnt(0) lgkmcnt(0)" ::: "memory");
        __builtin_amdgcn_s_barrier();
    }

    // ---- epilogue ----
    float p[4][4];   // dot partial -> c_pred
#pragma unroll
    for (int m = 0; m < 4; ++m)
#pragma unroll
        for (int j = 0; j < 4; ++j) {
            float s = 0.f;
#pragma unroll
            for (int n = 0; n < 4; ++n) {
                float v = acc[m][n][j] + bvals[n];
                v = v > 0.f ? v : 0.01f * v;
                acc[m][n][j] = v;           // ctx stored back into acc
                s += v * wvals[n];
            }
            s += __shfl_xor(s, 1);
            s += __shfl_xor(s, 2);
            s += __shfl_xor(s, 4);
            s += __shfl_xor(s, 8);
            p[m][j] = s;
        }
    if (lo16 == 0) {
#pragma unroll
        for (int m = 0; m < 4; ++m)
#pragma unroll
            for (int j = 0; j < 4; ++j)
                sm.epi.pl[wm * 64 + m * 16 + hi * 4 + j][wn] = p[m][j];
    }
    __builtin_amdgcn_s_barrier();
#pragma unroll
    for (int m = 0; m < 4; ++m)
#pragma unroll
        for (int j = 0; j < 4; ++j) {
            const int rg = wm * 64 + m * 16 + hi * 4 + j;
            const float z = sm.epi.pl[rg][0] + sm.epi.pl[rg][1] + bp_val;
            p[m][j] = 1.f / (1.f + __expf(-z));
        }
    if (wn == 0 && lo16 == 0) {
        if (pw) {
#pragma unroll
            for (int m = 0; m < 4; ++m) {
                float4 v = make_float4(p[m][0], p[m][1], p[m][2], p[m][3]);
                *(float4*)(pw + (size_t)k * B_SZ + brow + wm * 64 + m * 16 + hi * 4) = v;
            }
        } else {
#pragma unroll
            for (int m = 0; m < 4; ++m)
#pragma unroll
                for (int j = 0; j < 4; ++j) {
                    const int b = brow + wm * 64 + m * 16 + hi * 4 + j;
                    out[OUT_EMB + (size_t)b * K_SZ + k] = p[m][j];
                }
        }
    }
    // c_emb: wn==1 ships (1-p)*ctx_neg through LDS (stage region is dead; 33 KB fits)
    if (wn == 1) {
#pragma unroll
        for (int m = 0; m < 4; ++m)
#pragma unroll
            for (int n = 0; n < 4; ++n)
#pragma unroll
                for (int j = 0; j < 4; ++j)
                    sm.epi.ex[wm * 64 + m * 16 + hi * 4 + j][n * 16 + lo16] =
                        (1.f - p[m][j]) * acc[m][n][j];
    }
    __builtin_amdgcn_s_barrier();
    if (wn == 0) {
#pragma unroll
        for (int m = 0; m < 4; ++m)
#pragma unroll
            for (int n = 0; n < 4; ++n)
#pragma unroll
                for (int j = 0; j < 4; ++j) {
                    const int rl = wm * 64 + m * 16 + hi * 4 + j;
                    const int b = brow + rl;
                    const int e = n * 16 + lo16;
                    out[((size_t)b * K_SZ + k) * E_SZ + e] =
                        p[m][j] * acc[m][n][j] + sm.epi.ex[rl][e];
                }
    }
}

// ---------------- no-ws fallback (correctness insurance) ----------------
__global__ void __launch_bounds__(128) fallback_kernel(
    const float* __restrict__ x, const float* __restrict__ W,
    const float* __restrict__ bias, const float* __restrict__ wpv,
    const float* __restrict__ bpp, float* __restrict__ out) {
    const int k = blockIdx.y;
    const int b0 = blockIdx.x * 8;
    const int o = threadIdx.x;
    __shared__ float xs[8][1024];
    __shared__ float red[2];
    __shared__ float exch[64];
    for (int idx = threadIdx.x; idx < 8 * 1024; idx += 128)
        xs[idx >> 10][idx & 1023] = x[(size_t)(b0 + (idx >> 10)) * IN_SZ + (idx & 1023)];
    __syncthreads();
    float a[8] = {};
    for (int i = 0; i < 1024; ++i) {
        float wv = W[((size_t)k * IN_SZ + i) * TWOE + o];
#pragma unroll
        for (int bb = 0; bb < 8; ++bb) a[bb] += xs[bb][i] * wv;
    }
    const float bo = bias[k * TWOE + o], wo = wpv[o], bpv = *bpp;
    for (int bb = 0; bb < 8; ++bb) {
        float c = a[bb] + bo;
        c = c > 0.f ? c : 0.01f * c;
        float s = c * wo;
        for (int off = 1; off < 64; off <<= 1) s += __shfl_xor(s, off);
        if ((threadIdx.x & 63) == 0) red[threadIdx.x >> 6] = s;
        __syncthreads();
        float p = 1.f / (1.f + expf(-(red[0] + red[1] + bpv)));
        if (o >= 64) exch[o - 64] = (1.f - p) * c;
        __syncthreads();
        if (o < 64) out[((size_t)(b0 + bb) * K_SZ + k) * E_SZ + o] = p * c + exch[o];
        if (o == 0) out[OUT_EMB + (size_t)(b0 + bb) * K_SZ + k] = p;
        __syncthreads();
    }
}

extern "C" void kernel_launch(void* const* d_in, const int* in_sizes, int n_in,
                              void* d_out, int out_size, void* d_ws, size_t ws_size,
                              hipStream_t stream) {
    const float* x = (const float*)d_in[0];
    const float* W = (const float*)d_in[1];
    const float* bias = (const float*)d_in[2];
    const float* wp = (const float*)d_in[3];
    const float* bp = (const float*)d_in[4];
    float* out = (float*)d_out;

    const size_t X_ELEMS = (size_t)B_SZ * IN_SZ;
    const size_t WT_ELEMS = (size_t)K_SZ * TWOE * IN_SZ;
    const size_t PW_ELEMS = (size_t)K_SZ * B_SZ;
    const size_t NEED_BASE = (X_ELEMS + WT_ELEMS) * sizeof(u16);
    const size_t NEED_FULL = NEED_BASE + PW_ELEMS * sizeof(float);

    if (ws_size >= NEED_BASE) {
        u16* xb = (u16*)d_ws;
        u16* wt = xb + X_ELEMS;
        float* pw = (ws_size >= NEED_FULL) ? (float*)(wt + WT_ELEMS) : nullptr;
        int n4 = (int)(X_ELEMS / 4);
        cvt_x<<<dim3((n4 + 255) / 256), 256, 0, stream>>>(x, xb, n4);
        cvt_w<<<dim3(16, 128), 256, 0, stream>>>(W, wt);
        fused_main<<<dim3(2048), 256, 0, stream>>>(xb, wt, bias, wp, bp, out, pw);
        if (pw) cvt_pred<<<dim3(16), 256, 0, stream>>>(pw, out);
    } else {
        fallback_kernel<<<dim3(B_SZ / 8, K_SZ), 128, 0, stream>>>(x, W, bias, wp, bp, out);
    }
}

// Round 9
// 114.858 us; speedup vs baseline: 1.2215x; 1.1062x over previous
//
#include <hip/hip_runtime.h>

typedef unsigned int u32;
typedef unsigned short u16;
typedef __attribute__((ext_vector_type(8))) __bf16 bf16x8;
typedef __attribute__((ext_vector_type(4))) float f32x4;

#define B_SZ 2048
#define IN_SZ 1024
#define K_SZ 128
#define E_SZ 64
#define TWOE 128
static const size_t OUT_EMB = (size_t)B_SZ * K_SZ * E_SZ;  // 16,777,216

__device__ __forceinline__ u16 f2bf(float f) {
    u32 u = __builtin_bit_cast(u32, f);
    u32 r = u + 0x7fffu + ((u >> 16) & 1u);
    return (u16)(r >> 16);
}

__device__ __forceinline__ void async16(const void* g, void* l) {
    __builtin_amdgcn_global_load_lds((const __attribute__((address_space(1))) u32*)g,
                                     (__attribute__((address_space(3))) u32*)l, 16, 0, 0);
}

// ---------------- conversion kernels ----------------
__global__ void __launch_bounds__(256) cvt_x(const float* __restrict__ in, u16* __restrict__ outp, int n4) {
    int i = blockIdx.x * blockDim.x + threadIdx.x;
    if (i < n4) {
        float4 v = ((const float4*)in)[i];
        u32 lo = (u32)f2bf(v.x) | ((u32)f2bf(v.y) << 16);
        u32 hi = (u32)f2bf(v.z) | ((u32)f2bf(v.w) << 16);
        ((uint2*)outp)[i] = make_uint2(lo, hi);
    }
}

// W[k][i][o] f32 -> Wt[k][o][i] bf16.  grid (16 i-blocks, 128 k), 256 thr
__global__ void __launch_bounds__(256) cvt_w(const float* __restrict__ W, u16* __restrict__ wt) {
    __shared__ u16 tr[128][72];
    const int k = blockIdx.y, i0 = blockIdx.x * 64;
    const float* src = W + (size_t)k * IN_SZ * TWOE + (size_t)i0 * TWOE;
#pragma unroll
    for (int r = 0; r < 8; ++r) {
        int idx = r * 256 + threadIdx.x;
        int i = idx >> 5;
        int o = (idx & 31) * 4;
        float4 v = ((const float4*)src)[idx];
        tr[o + 0][i] = f2bf(v.x);
        tr[o + 1][i] = f2bf(v.y);
        tr[o + 2][i] = f2bf(v.z);
        tr[o + 3][i] = f2bf(v.w);
    }
    __syncthreads();
    const int o = threadIdx.x >> 1, h = threadIdx.x & 1;
    u16* dst = wt + ((size_t)(k * TWOE + o) * IN_SZ) + i0 + h * 32;
#pragma unroll
    for (int s = 0; s < 4; ++s) {
        uint4 v = *(const uint4*)&tr[o][h * 32 + s * 8];
        ((uint4*)dst)[s] = v;
    }
}

// pw[k][b] -> out_pred[b][k] transpose, 16 blocks x 256 thr
__global__ void __launch_bounds__(256) cvt_pred(const float* __restrict__ pw, float* __restrict__ out) {
    __shared__ float t[128][132];
    const int b0 = blockIdx.x * 128;
    const int tid = threadIdx.x;
#pragma unroll
    for (int i = 0; i < 16; ++i) {
        int idx = i * 256 + tid;
        int kk = idx >> 5, c4 = (idx & 31) * 4;
        float4 v = *(const float4*)(pw + (size_t)kk * B_SZ + b0 + c4);
        t[kk][c4 + 0] = v.x; t[kk][c4 + 1] = v.y; t[kk][c4 + 2] = v.z; t[kk][c4 + 3] = v.w;
    }
    __syncthreads();
#pragma unroll
    for (int i = 0; i < 16; ++i) {
        int idx = i * 256 + tid;
        int bl = idx >> 5, k4 = (idx & 31) * 4;
        float4 v = make_float4(t[k4 + 0][bl], t[k4 + 1][bl], t[k4 + 2][bl], t[k4 + 3][bl]);
        *(float4*)(out + OUT_EMB + (size_t)(b0 + bl) * K_SZ + k4) = v;
    }
}

// ---------------- fused GEMM + epilogue: 8-phase template ----------------
// Tile 256(b) x 256(two k's x 128 o) x K=1024, BK=64 split into 2 K-halves of 32.
// 512 threads = 8 waves (2M x 4N), per-wave 128x64, acc[8][4].
// LDS: A[2dbuf][2kh][256][32] bf16 (64 KB) + B same (64 KB).
// Per K-tile: 4 phases {ds_read 8|4 ; stage 1 K-half of t+1 ; barrier ; lgkm(0) ;
// setprio+16 MFMA ; [vmcnt(4) at ph2/ph4] ; barrier}. vmcnt never drains <4 in loop.
// grid: 512 blocks (8 brow x 64 kpair), XCD-chunked (8 kpair per XCD).
__global__ void __launch_bounds__(512, 2) fused_main(
    const u16* __restrict__ xb,   // [B][IN] bf16
    const u16* __restrict__ wt,   // [K][2E][IN] bf16
    const float* __restrict__ bias, const float* __restrict__ wpv,
    const float* __restrict__ bpp, float* __restrict__ out,
    float* __restrict__ pw) {
    __shared__ union {
        u16 stage[65536];   // A: (d*2+kh)*8192 .. ; B: 32768 + (d*2+kh)*8192
        struct { float pl[2][256][2]; float ex[2][256][66]; } epi;
    } sm;
    char* smb = (char*)&sm;

    const int tid = threadIdx.x;
    const int l = tid & 63, w = tid >> 6;    // lane, wave 0..7
    const int wm = w >> 2, wn = w & 3;       // 2M x 4N
    const int hi = l >> 4, lo16 = l & 15;
    const int q = l >> 2;                    // staging row-in-16
    const int swz = (l & 3) ^ ((l >> 3) & 3);

    // XCD-chunked mapping: xcd owns 8 kpairs; brow varies fastest
    const int id = blockIdx.x;
    const int xcd = id & 7, j = id >> 3;     // j 0..63
    const int kp = (xcd << 3) | (j >> 3);    // 0..63
    const int brow = (j & 7) << 8;           // 0..1792

    // staging source bases (pre-swizzled slot); LDS dest linear
    const u16* abase = xb + (size_t)(brow + w * 16 + q) * IN_SZ + swz * 8;
    const u16* bbase = wt + ((size_t)kp * 256 + w * 16 + q) * IN_SZ + swz * 8;

    // ds_read swizzled slot offset (bytes)
    const int xsl = (hi ^ ((lo16 >> 1) & 3)) << 4;

    f32x4 acc[8][4] = {};
    bf16x8 bfr[4];

    // stage one K-half (256 rows x 32 k = 16 KB): 2 loads/thread
    auto SA = [&](int d, int kh, int t) {
        u16* dst = (u16*)&sm + (d * 2 + kh) * 8192 + w * 512;
        const u16* src = abase + t * 64 + kh * 32;
        async16(src, dst);
        async16(src + (size_t)128 * IN_SZ, dst + 4096);
    };
    auto SB = [&](int d, int kh, int t) {
        u16* dst = (u16*)&sm + 32768 + (d * 2 + kh) * 8192 + w * 512;
        const u16* src = bbase + t * 64 + kh * 32;
        async16(src, dst);
        async16(src + (size_t)128 * IN_SZ, dst + 4096);
    };

#define VM4 asm volatile("s_waitcnt vmcnt(4)" ::: "memory")
#define VM0 asm volatile("s_waitcnt vmcnt(0)" ::: "memory")
#define NOPX ((void)0)
#define PHASE(D, KH, HALF, STG, VM)                                              \
    {                                                                            \
        bf16x8 af[4];                                                            \
        if ((HALF) == 0) {                                                       \
            const char* rb = smb + 65536 + ((D) * 2 + (KH)) * 16384;             \
            _Pragma("unroll") for (int n = 0; n < 4; ++n)                        \
                bfr[n] = *(const bf16x8*)(rb + (wn * 64 + n * 16 + lo16) * 64 + xsl); \
        }                                                                        \
        {                                                                        \
            const char* ra = smb + ((D) * 2 + (KH)) * 16384;                     \
            _Pragma("unroll") for (int mm = 0; mm < 4; ++mm)                     \
                af[mm] = *(const bf16x8*)(ra + (wm * 128 + ((HALF) * 4 + mm) * 16 + lo16) * 64 + xsl); \
        }                                                                        \
        STG;                                                                     \
        __builtin_amdgcn_s_barrier();                                            \
        asm volatile("s_waitcnt lgkmcnt(0)" ::: "memory");                       \
        __builtin_amdgcn_s_setprio(1);                                           \
        _Pragma("unroll") for (int mm = 0; mm < 4; ++mm)                         \
            _Pragma("unroll") for (int n = 0; n < 4; ++n)                        \
                acc[(HALF) * 4 + mm][n] = __builtin_amdgcn_mfma_f32_16x16x32_bf16( \
                    af[mm], bfr[n], acc[(HALF) * 4 + mm][n], 0, 0, 0);           \
        __builtin_amdgcn_s_setprio(0);                                           \
        VM;                                                                      \
        __builtin_amdgcn_s_barrier();                                            \
    }

    // prologue: stage tile 0 (4 K-half panels, 8 loads/thread)
    SA(0, 0, 0); SB(0, 0, 0); SA(0, 1, 0); SB(0, 1, 0);
    VM4;                       // retire kh0 (A0,B0); kh1 stays in flight
    __builtin_amdgcn_s_barrier();

#pragma unroll 1
    for (int tt = 0; tt < 14; tt += 2) {
        // tile tt (d=0), stage tt+1 into d=1
        PHASE(0, 0, 0, SA(1, 0, tt + 1), NOPX);
        PHASE(0, 0, 1, SB(1, 0, tt + 1), VM4);
        PHASE(0, 1, 0, SA(1, 1, tt + 1), NOPX);
        PHASE(0, 1, 1, SB(1, 1, tt + 1), VM4);
        // tile tt+1 (d=1), stage tt+2 into d=0
        PHASE(1, 0, 0, SA(0, 0, tt + 2), NOPX);
        PHASE(1, 0, 1, SB(0, 0, tt + 2), VM4);
        PHASE(1, 1, 0, SA(0, 1, tt + 2), NOPX);
        PHASE(1, 1, 1, SB(0, 1, tt + 2), VM4);
    }
    // tile 14 (d=0), stage 15 into d=1
    PHASE(0, 0, 0, SA(1, 0, 15), NOPX);
    PHASE(0, 0, 1, SB(1, 0, 15), VM4);
    PHASE(0, 1, 0, SA(1, 1, 15), NOPX);
    PHASE(0, 1, 1, SB(1, 1, 15), VM4);
    // tile 15 (d=1), drain
    PHASE(1, 0, 0, NOPX, NOPX);
    PHASE(1, 0, 1, NOPX, VM0);
    PHASE(1, 1, 0, NOPX, NOPX);
    PHASE(1, 1, 1, NOPX, VM0);
#undef PHASE

    // ---- epilogue ----
    const int ksel = wn >> 1, oh = wn & 1;   // k within pair; pos/neg half
    const int kglob = kp * 2 + ksel;
    const float bp_val = *bpp;
    float bvals[4], wvals[4];
#pragma unroll
    for (int n = 0; n < 4; ++n) {
        const int o = oh * 64 + n * 16 + lo16;
        bvals[n] = bias[kglob * TWOE + o];
        wvals[n] = wpv[o];
    }
    float p[8][4];
#pragma unroll
    for (int m = 0; m < 8; ++m)
#pragma unroll
        for (int jj = 0; jj < 4; ++jj) {
            float s = 0.f;
#pragma unroll
            for (int n = 0; n < 4; ++n) {
                float v = acc[m][n][jj] + bvals[n];
                v = v > 0.f ? v : 0.01f * v;
                acc[m][n][jj] = v;          // ctx kept in acc
                s += v * wvals[n];
            }
            s += __shfl_xor(s, 1);
            s += __shfl_xor(s, 2);
            s += __shfl_xor(s, 4);
            s += __shfl_xor(s, 8);
            p[m][jj] = s;
        }
    if (lo16 == 0) {
#pragma unroll
        for (int m = 0; m < 8; ++m)
#pragma unroll
            for (int jj = 0; jj < 4; ++jj)
                sm.epi.pl[ksel][wm * 128 + m * 16 + hi * 4 + jj][oh] = p[m][jj];
    }
    __builtin_amdgcn_s_barrier();
#pragma unroll
    for (int m = 0; m < 8; ++m)
#pragma unroll
        for (int jj = 0; jj < 4; ++jj) {
            const int rg = wm * 128 + m * 16 + hi * 4 + jj;
            const float z = sm.epi.pl[ksel][rg][0] + sm.epi.pl[ksel][rg][1] + bp_val;
            p[m][jj] = 1.f / (1.f + __expf(-z));
        }
    if (oh == 0 && lo16 == 0) {
        if (pw) {
#pragma unroll
            for (int m = 0; m < 8; ++m) {
                float4 v = make_float4(p[m][0], p[m][1], p[m][2], p[m][3]);
                *(float4*)(pw + (size_t)kglob * B_SZ + brow + wm * 128 + m * 16 + hi * 4) = v;
            }
        } else {
#pragma unroll
            for (int m = 0; m < 8; ++m)
#pragma unroll
                for (int jj = 0; jj < 4; ++jj) {
                    const int b = brow + wm * 128 + m * 16 + hi * 4 + jj;
                    out[OUT_EMB + (size_t)b * K_SZ + kglob] = p[m][jj];
                }
        }
    }
    // c_emb: neg waves (oh==1) ship (1-p)*ctx_neg via LDS; pos waves combine+store
    if (oh == 1) {
#pragma unroll
        for (int m = 0; m < 8; ++m)
#pragma unroll
            for (int n = 0; n < 4; ++n)
#pragma unroll
                for (int jj = 0; jj < 4; ++jj)
                    sm.epi.ex[ksel][wm * 128 + m * 16 + hi * 4 + jj][n * 16 + lo16] =
                        (1.f - p[m][jj]) * acc[m][n][jj];
    }
    __builtin_amdgcn_s_barrier();
    if (oh == 0) {
#pragma unroll
        for (int m = 0; m < 8; ++m)
#pragma unroll
            for (int n = 0; n < 4; ++n)
#pragma unroll
                for (int jj = 0; jj < 4; ++jj) {
                    const int rl = wm * 128 + m * 16 + hi * 4 + jj;
                    const int b = brow + rl;
                    const int e = n * 16 + lo16;
                    out[((size_t)b * K_SZ + kglob) * E_SZ + e] =
                        p[m][jj] * acc[m][n][jj] + sm.epi.ex[ksel][rl][e];
                }
    }
}

// ---------------- no-ws fallback (correctness insurance) ----------------
__global__ void __launch_bounds__(128) fallback_kernel(
    const float* __restrict__ x, const float* __restrict__ W,
    const float* __restrict__ bias, const float* __restrict__ wpv,
    const float* __restrict__ bpp, float* __restrict__ out) {
    const int k = blockIdx.y;
    const int b0 = blockIdx.x * 8;
    const int o = threadIdx.x;
    __shared__ float xs[8][1024];
    __shared__ float red[2];
    __shared__ float exch[64];
    for (int idx = threadIdx.x; idx < 8 * 1024; idx += 128)
        xs[idx >> 10][idx & 1023] = x[(size_t)(b0 + (idx >> 10)) * IN_SZ + (idx & 1023)];
    __syncthreads();
    float a[8] = {};
    for (int i = 0; i < 1024; ++i) {
        float wv = W[((size_t)k * IN_SZ + i) * TWOE + o];
#pragma unroll
        for (int bb = 0; bb < 8; ++bb) a[bb] += xs[bb][i] * wv;
    }
    const float bo = bias[k * TWOE + o], wo = wpv[o], bpv = *bpp;
    for (int bb = 0; bb < 8; ++bb) {
        float c = a[bb] + bo;
        c = c > 0.f ? c : 0.01f * c;
        float s = c * wo;
        for (int off = 1; off < 64; off <<= 1) s += __shfl_xor(s, off);
        if ((threadIdx.x & 63) == 0) red[threadIdx.x >> 6] = s;
        __syncthreads();
        float p = 1.f / (1.f + expf(-(red[0] + red[1] + bpv)));
        if (o >= 64) exch[o - 64] = (1.f - p) * c;
        __syncthreads();
        if (o < 64) out[((size_t)(b0 + bb) * K_SZ + k) * E_SZ + o] = p * c + exch[o];
        if (o == 0) out[OUT_EMB + (size_t)(b0 + bb) * K_SZ + k] = p;
        __syncthreads();
    }
}

extern "C" void kernel_launch(void* const* d_in, const int* in_sizes, int n_in,
                              void* d_out, int out_size, void* d_ws, size_t ws_size,
                              hipStream_t stream) {
    const float* x = (const float*)d_in[0];
    const float* W = (const float*)d_in[1];
    const float* bias = (const float*)d_in[2];
    const float* wp = (const float*)d_in[3];
    const float* bp = (const float*)d_in[4];
    float* out = (float*)d_out;

    const size_t X_ELEMS = (size_t)B_SZ * IN_SZ;
    const size_t WT_ELEMS = (size_t)K_SZ * TWOE * IN_SZ;
    const size_t PW_ELEMS = (size_t)K_SZ * B_SZ;
    const size_t NEED_BASE = (X_ELEMS + WT_ELEMS) * sizeof(u16);
    const size_t NEED_FULL = NEED_BASE + PW_ELEMS * sizeof(float);

    if (ws_size >= NEED_BASE) {
        u16* xb = (u16*)d_ws;
        u16* wt = xb + X_ELEMS;
        float* pw = (ws_size >= NEED_FULL) ? (float*)(wt + WT_ELEMS) : nullptr;
        int n4 = (int)(X_ELEMS / 4);
        cvt_x<<<dim3((n4 + 255) / 256), 256, 0, stream>>>(x, xb, n4);
        cvt_w<<<dim3(16, 128), 256, 0, stream>>>(W, wt);
        fused_main<<<dim3(512), 512, 0, stream>>>(xb, wt, bias, wp, bp, out, pw);
        if (pw) cvt_pred<<<dim3(16), 256, 0, stream>>>(pw, out);
    } else {
        fallback_kernel<<<dim3(B_SZ / 8, K_SZ), 128, 0, stream>>>(x, W, bias, wp, bp, out);
    }
}

// Round 10
// 114.829 us; speedup vs baseline: 1.2219x; 1.0003x over previous
//
#include <hip/hip_runtime.h>

typedef unsigned int u32;
typedef unsigned short u16;
typedef __attribute__((ext_vector_type(8))) __bf16 bf16x8;
typedef __attribute__((ext_vector_type(4))) float f32x4;

#define B_SZ 2048
#define IN_SZ 1024
#define K_SZ 128
#define E_SZ 64
#define TWOE 128
static const size_t OUT_EMB = (size_t)B_SZ * K_SZ * E_SZ;  // 16,777,216

__device__ __forceinline__ u16 f2bf(float f) {
    u32 u = __builtin_bit_cast(u32, f);
    u32 r = u + 0x7fffu + ((u >> 16) & 1u);
    return (u16)(r >> 16);
}

__device__ __forceinline__ void async16(const void* g, void* l) {
    __builtin_amdgcn_global_load_lds((const __attribute__((address_space(1))) u32*)g,
                                     (__attribute__((address_space(3))) u32*)l, 16, 0, 0);
}

// ---------------- conversion kernels ----------------
__global__ void __launch_bounds__(256) cvt_x(const float* __restrict__ in, u16* __restrict__ outp, int n4) {
    int i = blockIdx.x * blockDim.x + threadIdx.x;
    if (i < n4) {
        float4 v = ((const float4*)in)[i];
        u32 lo = (u32)f2bf(v.x) | ((u32)f2bf(v.y) << 16);
        u32 hi = (u32)f2bf(v.z) | ((u32)f2bf(v.w) << 16);
        ((uint2*)outp)[i] = make_uint2(lo, hi);
    }
}

// W[k][i][o] f32 -> Wt[k][o][i] bf16.  grid (16 i-blocks, 128 k), 256 thr
__global__ void __launch_bounds__(256) cvt_w(const float* __restrict__ W, u16* __restrict__ wt) {
    __shared__ u16 tr[128][72];
    const int k = blockIdx.y, i0 = blockIdx.x * 64;
    const float* src = W + (size_t)k * IN_SZ * TWOE + (size_t)i0 * TWOE;
#pragma unroll
    for (int r = 0; r < 8; ++r) {
        int idx = r * 256 + threadIdx.x;
        int i = idx >> 5;
        int o = (idx & 31) * 4;
        float4 v = ((const float4*)src)[idx];
        tr[o + 0][i] = f2bf(v.x);
        tr[o + 1][i] = f2bf(v.y);
        tr[o + 2][i] = f2bf(v.z);
        tr[o + 3][i] = f2bf(v.w);
    }
    __syncthreads();
    const int o = threadIdx.x >> 1, h = threadIdx.x & 1;
    u16* dst = wt + ((size_t)(k * TWOE + o) * IN_SZ) + i0 + h * 32;
#pragma unroll
    for (int s = 0; s < 4; ++s) {
        uint4 v = *(const uint4*)&tr[o][h * 32 + s * 8];
        ((uint4*)dst)[s] = v;
    }
}

// pw[k][b] -> out_pred[b][k] transpose, 16 blocks x 256 thr
__global__ void __launch_bounds__(256) cvt_pred(const float* __restrict__ pw, float* __restrict__ out) {
    __shared__ float t[128][132];
    const int b0 = blockIdx.x * 128;
    const int tid = threadIdx.x;
#pragma unroll
    for (int i = 0; i < 16; ++i) {
        int idx = i * 256 + tid;
        int kk = idx >> 5, c4 = (idx & 31) * 4;
        float4 v = *(const float4*)(pw + (size_t)kk * B_SZ + b0 + c4);
        t[kk][c4 + 0] = v.x; t[kk][c4 + 1] = v.y; t[kk][c4 + 2] = v.z; t[kk][c4 + 3] = v.w;
    }
    __syncthreads();
#pragma unroll
    for (int i = 0; i < 16; ++i) {
        int idx = i * 256 + tid;
        int bl = idx >> 5, k4 = (idx & 31) * 4;
        float4 v = make_float4(t[k4 + 0][bl], t[k4 + 1][bl], t[k4 + 2][bl], t[k4 + 3][bl]);
        *(float4*)(out + OUT_EMB + (size_t)(b0 + bl) * K_SZ + k4) = v;
    }
}

// ---------------- fused GEMM + epilogue: counted-vmcnt phase loop ----------------
// Tile 256(b) x 256(two k's x 128 o) x K=1024; K split into 32 panels of 32.
// 512 threads = 8 waves (2M x 4N), per-wave 128x64, acc[8][4].
// LDS: A[2dbuf][2kh][256][32] bf16 (64 KB) + B same (64 KB).
// 32 phases, each: {ds_read af[8]+bfr[4] ; stage A+B panel of (t+1, same kh) ;
// setprio + 32 MFMA (compiler emits fine-grained lgkmcnt) ; vmcnt(4) ; ONE barrier}.
// vmcnt(4) retires exactly the panel read next phase (2-phase stage->read distance).
// R9's extra barrier + explicit lgkmcnt(0) per micro-phase were the ~60% stall.
// grid: 512 blocks (8 brow x 64 kpair), XCD-chunked (8 kpair per XCD).
__global__ void __launch_bounds__(512, 2) fused_main(
    const u16* __restrict__ xb,   // [B][IN] bf16
    const u16* __restrict__ wt,   // [K][2E][IN] bf16
    const float* __restrict__ bias, const float* __restrict__ wpv,
    const float* __restrict__ bpp, float* __restrict__ out,
    float* __restrict__ pw) {
    __shared__ union {
        u16 stage[65536];   // A: (d*2+kh)*8192 .. ; B: 32768 + (d*2+kh)*8192
        struct { float pl[2][256][2]; float ex[2][256][66]; } epi;
    } sm;
    char* smb = (char*)&sm;

    const int tid = threadIdx.x;
    const int l = tid & 63, w = tid >> 6;    // lane, wave 0..7
    const int wm = w >> 2, wn = w & 3;       // 2M x 4N
    const int hi = l >> 4, lo16 = l & 15;
    const int q = l >> 2;                    // staging row-in-16
    const int swz = (l & 3) ^ ((l >> 3) & 3);

    // XCD-chunked mapping: xcd owns 8 kpairs; brow varies fastest
    const int id = blockIdx.x;
    const int xcd = id & 7, j = id >> 3;     // j 0..63
    const int kp = (xcd << 3) | (j >> 3);    // 0..63
    const int brow = (j & 7) << 8;           // 0..1792

    // staging source bases (pre-swizzled slot); LDS dest linear
    const u16* abase = xb + (size_t)(brow + w * 16 + q) * IN_SZ + swz * 8;
    const u16* bbase = wt + ((size_t)kp * 256 + w * 16 + q) * IN_SZ + swz * 8;

    // ds_read swizzled slot offset (bytes)
    const int xsl = (hi ^ ((lo16 >> 1) & 3)) << 4;

    f32x4 acc[8][4] = {};

    // stage one K-half panel (256 rows x 32 k = 16 KB): 2 loads/thread
    auto SA = [&](int d, int kh, int t) {
        u16* dst = (u16*)&sm + (d * 2 + kh) * 8192 + w * 512;
        const u16* src = abase + t * 64 + kh * 32;
        async16(src, dst);
        async16(src + (size_t)128 * IN_SZ, dst + 4096);
    };
    auto SB = [&](int d, int kh, int t) {
        u16* dst = (u16*)&sm + 32768 + (d * 2 + kh) * 8192 + w * 512;
        const u16* src = bbase + t * 64 + kh * 32;
        async16(src, dst);
        async16(src + (size_t)128 * IN_SZ, dst + 4096);
    };

#define NOPX ((void)0)
// One phase: read panel (D,KH), stage via STG (comma-expr), 32 MFMA, counted wait, barrier.
#define PH(D, KH, STG, VMW)                                                      \
    {                                                                            \
        const char* ra = smb + ((D) * 2 + (KH)) * 16384;                         \
        const char* rb = smb + 65536 + ((D) * 2 + (KH)) * 16384;                 \
        bf16x8 af[8], bfr[4];                                                    \
        _Pragma("unroll") for (int n = 0; n < 4; ++n)                            \
            bfr[n] = *(const bf16x8*)(rb + (wn * 64 + n * 16 + lo16) * 64 + xsl); \
        _Pragma("unroll") for (int mm = 0; mm < 8; ++mm)                         \
            af[mm] = *(const bf16x8*)(ra + (wm * 128 + mm * 16 + lo16) * 64 + xsl); \
        STG;                                                                     \
        __builtin_amdgcn_s_setprio(1);                                           \
        _Pragma("unroll") for (int mm = 0; mm < 8; ++mm)                         \
            _Pragma("unroll") for (int n = 0; n < 4; ++n)                        \
                acc[mm][n] = __builtin_amdgcn_mfma_f32_16x16x32_bf16(            \
                    af[mm], bfr[n], acc[mm][n], 0, 0, 0);                        \
        __builtin_amdgcn_s_setprio(0);                                           \
        asm volatile("s_waitcnt " VMW ::: "memory");                             \
        __builtin_amdgcn_s_barrier();                                            \
    }

    // prologue: stage tile 0 (both kh panels, 8 loads/thread); retire kh0, keep kh1 in flight
    SA(0, 0, 0); SB(0, 0, 0); SA(0, 1, 0); SB(0, 1, 0);
    asm volatile("s_waitcnt vmcnt(4)" ::: "memory");
    __builtin_amdgcn_s_barrier();

#pragma unroll 1
    for (int tt = 0; tt < 14; tt += 2) {
        PH(0, 0, (SA(1, 0, tt + 1), SB(1, 0, tt + 1)), "vmcnt(4)");
        PH(0, 1, (SA(1, 1, tt + 1), SB(1, 1, tt + 1)), "vmcnt(4)");
        PH(1, 0, (SA(0, 0, tt + 2), SB(0, 0, tt + 2)), "vmcnt(4)");
        PH(1, 1, (SA(0, 1, tt + 2), SB(0, 1, tt + 2)), "vmcnt(4)");
    }
    // tile 14 (d=0), stage 15 into d=1
    PH(0, 0, (SA(1, 0, 15), SB(1, 0, 15)), "vmcnt(4)");
    PH(0, 1, (SA(1, 1, 15), SB(1, 1, 15)), "vmcnt(4)");
    // tile 15 (d=1), drain
    PH(1, 0, NOPX, "vmcnt(0)");
    PH(1, 1, NOPX, "vmcnt(0)");
#undef PH

    // ---- epilogue ----
    const int ksel = wn >> 1, oh = wn & 1;   // k within pair; pos/neg half
    const int kglob = kp * 2 + ksel;
    const float bp_val = *bpp;
    float bvals[4], wvals[4];
#pragma unroll
    for (int n = 0; n < 4; ++n) {
        const int o = oh * 64 + n * 16 + lo16;
        bvals[n] = bias[kglob * TWOE + o];
        wvals[n] = wpv[o];
    }
    float p[8][4];
#pragma unroll
    for (int m = 0; m < 8; ++m)
#pragma unroll
        for (int jj = 0; jj < 4; ++jj) {
            float s = 0.f;
#pragma unroll
            for (int n = 0; n < 4; ++n) {
                float v = acc[m][n][jj] + bvals[n];
                v = v > 0.f ? v : 0.01f * v;
                acc[m][n][jj] = v;          // ctx kept in acc
                s += v * wvals[n];
            }
            s += __shfl_xor(s, 1);
            s += __shfl_xor(s, 2);
            s += __shfl_xor(s, 4);
            s += __shfl_xor(s, 8);
            p[m][jj] = s;
        }
    if (lo16 == 0) {
#pragma unroll
        for (int m = 0; m < 8; ++m)
#pragma unroll
            for (int jj = 0; jj < 4; ++jj)
                sm.epi.pl[ksel][wm * 128 + m * 16 + hi * 4 + jj][oh] = p[m][jj];
    }
    __builtin_amdgcn_s_barrier();
#pragma unroll
    for (int m = 0; m < 8; ++m)
#pragma unroll
        for (int jj = 0; jj < 4; ++jj) {
            const int rg = wm * 128 + m * 16 + hi * 4 + jj;
            const float z = sm.epi.pl[ksel][rg][0] + sm.epi.pl[ksel][rg][1] + bp_val;
            p[m][jj] = 1.f / (1.f + __expf(-z));
        }
    if (oh == 0 && lo16 == 0) {
        if (pw) {
#pragma unroll
            for (int m = 0; m < 8; ++m) {
                float4 v = make_float4(p[m][0], p[m][1], p[m][2], p[m][3]);
                *(float4*)(pw + (size_t)kglob * B_SZ + brow + wm * 128 + m * 16 + hi * 4) = v;
            }
        } else {
#pragma unroll
            for (int m = 0; m < 8; ++m)
#pragma unroll
                for (int jj = 0; jj < 4; ++jj) {
                    const int b = brow + wm * 128 + m * 16 + hi * 4 + jj;
                    out[OUT_EMB + (size_t)b * K_SZ + kglob] = p[m][jj];
                }
        }
    }
    // c_emb: neg waves (oh==1) ship (1-p)*ctx_neg via LDS; pos waves combine+store
    if (oh == 1) {
#pragma unroll
        for (int m = 0; m < 8; ++m)
#pragma unroll
            for (int n = 0; n < 4; ++n)
#pragma unroll
                for (int jj = 0; jj < 4; ++jj)
                    sm.epi.ex[ksel][wm * 128 + m * 16 + hi * 4 + jj][n * 16 + lo16] =
                        (1.f - p[m][jj]) * acc[m][n][jj];
    }
    __builtin_amdgcn_s_barrier();
    if (oh == 0) {
#pragma unroll
        for (int m = 0; m < 8; ++m)
#pragma unroll
            for (int n = 0; n < 4; ++n)
#pragma unroll
                for (int jj = 0; jj < 4; ++jj) {
                    const int rl = wm * 128 + m * 16 + hi * 4 + jj;
                    const int b = brow + rl;
                    const int e = n * 16 + lo16;
                    out[((size_t)b * K_SZ + kglob) * E_SZ + e] =
                        p[m][jj] * acc[m][n][jj] + sm.epi.ex[ksel][rl][e];
                }
    }
}

// ---------------- no-ws fallback (correctness insurance) ----------------
__global__ void __launch_bounds__(128) fallback_kernel(
    const float* __restrict__ x, const float* __restrict__ W,
    const float* __restrict__ bias, const float* __restrict__ wpv,
    const float* __restrict__ bpp, float* __restrict__ out) {
    const int k = blockIdx.y;
    const int b0 = blockIdx.x * 8;
    const int o = threadIdx.x;
    __shared__ float xs[8][1024];
    __shared__ float red[2];
    __shared__ float exch[64];
    for (int idx = threadIdx.x; idx < 8 * 1024; idx += 128)
        xs[idx >> 10][idx & 1023] = x[(size_t)(b0 + (idx >> 10)) * IN_SZ + (idx & 1023)];
    __syncthreads();
    float a[8] = {};
    for (int i = 0; i < 1024; ++i) {
        float wv = W[((size_t)k * IN_SZ + i) * TWOE + o];
#pragma unroll
        for (int bb = 0; bb < 8; ++bb) a[bb] += xs[bb][i] * wv;
    }
    const float bo = bias[k * TWOE + o], wo = wpv[o], bpv = *bpp;
    for (int bb = 0; bb < 8; ++bb) {
        float c = a[bb] + bo;
        c = c > 0.f ? c : 0.01f * c;
        float s = c * wo;
        for (int off = 1; off < 64; off <<= 1) s += __shfl_xor(s, off);
        if ((threadIdx.x & 63) == 0) red[threadIdx.x >> 6] = s;
        __syncthreads();
        float p = 1.f / (1.f + expf(-(red[0] + red[1] + bpv)));
        if (o >= 64) exch[o - 64] = (1.f - p) * c;
        __syncthreads();
        if (o < 64) out[((size_t)(b0 + bb) * K_SZ + k) * E_SZ + o] = p * c + exch[o];
        if (o == 0) out[OUT_EMB + (size_t)(b0 + bb) * K_SZ + k] = p;
        __syncthreads();
    }
}

extern "C" void kernel_launch(void* const* d_in, const int* in_sizes, int n_in,
                              void* d_out, int out_size, void* d_ws, size_t ws_size,
                              hipStream_t stream) {
    const float* x = (const float*)d_in[0];
    const float* W = (const float*)d_in[1];
    const float* bias = (const float*)d_in[2];
    const float* wp = (const float*)d_in[3];
    const float* bp = (const float*)d_in[4];
    float* out = (float*)d_out;

    const size_t X_ELEMS = (size_t)B_SZ * IN_SZ;
    const size_t WT_ELEMS = (size_t)K_SZ * TWOE * IN_SZ;
    const size_t PW_ELEMS = (size_t)K_SZ * B_SZ;
    const size_t NEED_BASE = (X_ELEMS + WT_ELEMS) * sizeof(u16);
    const size_t NEED_FULL = NEED_BASE + PW_ELEMS * sizeof(float);

    if (ws_size >= NEED_BASE) {
        u16* xb = (u16*)d_ws;
        u16* wt = xb + X_ELEMS;
        float* pw = (ws_size >= NEED_FULL) ? (float*)(wt + WT_ELEMS) : nullptr;
        int n4 = (int)(X_ELEMS / 4);
        cvt_x<<<dim3((n4 + 255) / 256), 256, 0, stream>>>(x, xb, n4);
        cvt_w<<<dim3(16, 128), 256, 0, stream>>>(W, wt);
        fused_main<<<dim3(512), 512, 0, stream>>>(xb, wt, bias, wp, bp, out, pw);
        if (pw) cvt_pred<<<dim3(16), 256, 0, stream>>>(pw, out);
    } else {
        fallback_kernel<<<dim3(B_SZ / 8, K_SZ), 128, 0, stream>>>(x, W, bias, wp, bp, out);
    }
}